// Round 7
// baseline (293.399 us; speedup 1.0000x reference)
//
#include <hip/hip_runtime.h>
#include <hip/hip_bf16.h>
#include <stdint.h>

#define D_MODEL 1024
#define NHEADS  16
#define DKH     64
#define BATCH   2
#define SEQ     2048
#define MTOT    (BATCH*SEQ)   // 4096

typedef __attribute__((ext_vector_type(8)))  short bf16x8;   // 8 bf16 = 4 VGPRs
typedef __attribute__((ext_vector_type(4)))  float f32x4;
typedef __attribute__((ext_vector_type(16))) float f32x16;
typedef __attribute__((ext_vector_type(4)))  unsigned int u32x4;

__device__ inline unsigned short f2bf(float f) {
    __hip_bfloat16 h = __float2bfloat16(f);
    return *reinterpret_cast<unsigned short*>(&h);
}
__device__ inline unsigned int pack2bf(float a, float b) {   // low=a, high=b (RNE)
    __hip_bfloat162 h = __float22bfloat162_rn(float2{a, b});
    return *reinterpret_cast<unsigned int*>(&h);
}

// async global->LDS, 16B per lane; LDS dest = wave-uniform base + lane*16 (m97/m104)
__device__ inline void gl2lds16(const unsigned short* g, unsigned short* l) {
    __builtin_amdgcn_global_load_lds(
        (const __attribute__((address_space(1))) void*)g,
        (__attribute__((address_space(3))) void*)l,
        16, 0, 0);
}

// One-shot fp32 -> bf16 conversion of x and the 4 weight matrices.
__global__ __launch_bounds__(256) void cvt_all(
    const float* __restrict__ x,  const float* __restrict__ wq,
    const float* __restrict__ wk, const float* __restrict__ wv,
    const float* __restrict__ wo,
    unsigned short* __restrict__ xb,  unsigned short* __restrict__ wqb,
    unsigned short* __restrict__ wkb, unsigned short* __restrict__ wvb,
    unsigned short* __restrict__ wob)
{
    int bid = blockIdx.x;
    const float* s; unsigned short* d; size_t base;
    if (bid < 2048) { s = x; d = xb; base = (size_t)bid * 2048; }
    else {
        int w  = (bid - 2048) >> 9;
        int wb = (bid - 2048) & 511;
        s = (w == 0) ? wq : (w == 1) ? wk : (w == 2) ? wv : wo;
        d = (w == 0) ? wqb : (w == 1) ? wkb : (w == 2) ? wvb : wob;
        base = (size_t)wb * 2048;
    }
    size_t i = base + (size_t)threadIdx.x * 8;
    float4 a = *(const float4*)(s + i);
    float4 b = *(const float4*)(s + i + 4);
    unsigned short t8[8] = {f2bf(a.x), f2bf(a.y), f2bf(a.z), f2bf(a.w),
                            f2bf(b.x), f2bf(b.y), f2bf(b.z), f2bf(b.w)};
    *(uint4*)(d + i) = *(uint4*)t8;
}

// Fused QKV projection, DEPTH-2 counted-vmcnt pipeline (unchanged from r5).
__global__ __launch_bounds__(512, 2) void qkv_fused(
    const unsigned short* __restrict__ X,
    const unsigned short* __restrict__ Wq,
    const unsigned short* __restrict__ Wk,
    const unsigned short* __restrict__ Wv,
    unsigned short* __restrict__ Qo,
    unsigned short* __restrict__ Ko,
    unsigned short* __restrict__ Vto,
    float qscale)
{
    const int id = blockIdx.x + 32 * blockIdx.y;   // 256 blocks, 256%8==0
    const int sw = (id & 7) * 32 + (id >> 3);      // XCD c -> contiguous chunk
    const int m0 = (sw & 31) * 128;                // x-row tile
    const int n0 = (sw >> 5) * 128;                // weight-row tile

    // [buf 0..2][128 x 32 shorts] per tile; 4 tiles x 3 buf = 96 KiB
    __shared__ __align__(16) unsigned short Xs[3][128 * 32];
    __shared__ __align__(16) unsigned short Bq[3][128 * 32];
    __shared__ __align__(16) unsigned short Bk[3][128 * 32];
    __shared__ __align__(16) unsigned short Bv[3][128 * 32];

    const int t = threadIdx.x;
    const int wave = t >> 6, lane = t & 63;
    const int quad = lane >> 4, l16 = lane & 15;
    const int wm = (wave >> 2) * 64;
    const int wn = (wave & 3) * 32;

    // staging: wave w covers tile (w>>1), rows [(w&1)*64, +64) in 4 groups of 16
    const int stile = wave >> 1;
    const int srow  = (wave & 1) * 64 + (lane >> 2);
    const int schk  = (lane & 3) * 8;
    const unsigned short* gsrc = (stile == 0) ? X : (stile == 1) ? Wq :
                                 (stile == 2) ? Wk : Wv;
    const int grow0 = (stile == 0) ? m0 : n0;
    const unsigned short* Sg = gsrc + (size_t)(grow0 + srow) * D_MODEL + schk;
    unsigned short* LdB = ((stile == 0) ? &Xs[0][0] : (stile == 1) ? &Bq[0][0] :
                           (stile == 2) ? &Bk[0][0] : &Bv[0][0])
                          + (wave & 1) * 64 * 32;   // wave-uniform base

    f32x4 aQ[4][2] = {}, aK[4][2] = {}, aV[2][4] = {};

#define QKV_STAGE(BUF, STEP)                                                  \
    do {                                                                      \
        _Pragma("unroll")                                                     \
        for (int g = 0; g < 4; ++g)                                           \
            gl2lds16(Sg + (STEP) * 32 + (size_t)g * 16 * D_MODEL,             \
                     LdB + (BUF) * 4096 + g * 512);                           \
    } while (0)

#define QKV_COMP(BUF)                                                         \
    do {                                                                      \
        bf16x8 xa[4], fq[2], fk[2], fv[2];                                    \
        _Pragma("unroll")                                                     \
        for (int i = 0; i < 4; ++i)                                           \
            xa[i] = *(const bf16x8*)(&Xs[(BUF)][0] + (wm + i * 16 + l16) * 32 + quad * 8); \
        _Pragma("unroll")                                                     \
        for (int j = 0; j < 2; ++j) {                                         \
            fq[j] = *(const bf16x8*)(&Bq[(BUF)][0] + (wn + j * 16 + l16) * 32 + quad * 8); \
            fk[j] = *(const bf16x8*)(&Bk[(BUF)][0] + (wn + j * 16 + l16) * 32 + quad * 8); \
            fv[j] = *(const bf16x8*)(&Bv[(BUF)][0] + (wn + j * 16 + l16) * 32 + quad * 8); \
        }                                                                     \
        _Pragma("unroll")                                                     \
        for (int i = 0; i < 4; ++i)                                           \
            _Pragma("unroll")                                                 \
            for (int j = 0; j < 2; ++j) {                                     \
                aQ[i][j] = __builtin_amdgcn_mfma_f32_16x16x32_bf16(xa[i], fq[j], aQ[i][j], 0, 0, 0); \
                aK[i][j] = __builtin_amdgcn_mfma_f32_16x16x32_bf16(xa[i], fk[j], aK[i][j], 0, 0, 0); \
                aV[j][i] = __builtin_amdgcn_mfma_f32_16x16x32_bf16(fv[j], xa[i], aV[j][i], 0, 0, 0); \
            }                                                                 \
    } while (0)

    QKV_STAGE(0, 0);          // 4 loads in flight
    QKV_STAGE(1, 1);          // 8 loads in flight
    for (int step = 0; step < 32; ++step) {
        __builtin_amdgcn_s_barrier();            // A: compute(step-1) done everywhere
        const int nxt = step + 2;                //    -> B[(step+2)%3] is free (WAR)
        if (nxt < 32) QKV_STAGE(nxt % 3, nxt);   // 12 in flight
        if (step < 30)      asm volatile("s_waitcnt vmcnt(8)" ::: "memory");  // stage(step) landed
        else if (step < 31) asm volatile("s_waitcnt vmcnt(4)" ::: "memory");
        else                asm volatile("s_waitcnt vmcnt(0)" ::: "memory");
        __builtin_amdgcn_s_barrier();            // B: everyone's stage(step) visible
        __builtin_amdgcn_sched_barrier(0);
        QKV_COMP(step % 3);
    }
#undef QKV_STAGE
#undef QKV_COMP

    #pragma unroll
    for (int i = 0; i < 4; ++i)
        #pragma unroll
        for (int j = 0; j < 2; ++j)
            #pragma unroll
            for (int r = 0; r < 4; ++r) {
                const int mr = m0 + wm + i * 16 + quad * 4 + r;
                const int nc = n0 + wn + j * 16 + l16;
                Qo[(size_t)mr * D_MODEL + nc] = f2bf(aQ[i][j][r] * qscale);
                Ko[(size_t)mr * D_MODEL + nc] = f2bf(aK[i][j][r]);
                // V^T: row = weight-side of aV, col = x-side
                Vto[(size_t)(n0 + wn + j * 16 + quad * 4 + r) * MTOT
                    + (m0 + wm + i * 16 + l16)] = f2bf(aV[j][i][r]);
            }
}

// Output projection C_fp32[M,N] = A[M,K] @ W[N,K]^T (unchanged from r5).
__global__ __launch_bounds__(512, 2) void gemm_o(
    const unsigned short* __restrict__ A,
    const unsigned short* __restrict__ W,
    float* __restrict__ C)
{
    const int id = blockIdx.x + 32 * blockIdx.y;
    const int sw = (id & 7) * 32 + (id >> 3);
    const int m0 = (sw & 31) * 128, n0 = (sw >> 5) * 128;

    __shared__ __align__(16) unsigned short As[3][128 * 32];
    __shared__ __align__(16) unsigned short Bs[3][128 * 32];   // 48 KiB

    const int t = threadIdx.x, wave = t >> 6, lane = t & 63;
    const int quad = lane >> 4, l16 = lane & 15;
    const int wm = (wave >> 2) * 64, wn = (wave & 3) * 32;

    // staging: wave w covers tile (w>>2), rows [(w&3)*32, +32) in 2 groups of 16
    const int stile = wave >> 2;
    const int srow  = (wave & 3) * 32 + (lane >> 2);
    const int schk  = (lane & 3) * 8;
    const unsigned short* Sg = (stile ? W : A)
        + (size_t)((stile ? n0 : m0) + srow) * D_MODEL + schk;
    unsigned short* LdB = (stile ? &Bs[0][0] : &As[0][0]) + (wave & 3) * 32 * 32;

    f32x4 acc[4][2] = {};

#define O_STAGE(BUF, STEP)                                                    \
    do {                                                                      \
        _Pragma("unroll")                                                     \
        for (int g = 0; g < 2; ++g)                                           \
            gl2lds16(Sg + (STEP) * 32 + (size_t)g * 16 * D_MODEL,             \
                     LdB + (BUF) * 4096 + g * 512);                           \
    } while (0)

#define O_COMP(BUF)                                                           \
    do {                                                                      \
        bf16x8 af[4], bfr[2];                                                 \
        _Pragma("unroll")                                                     \
        for (int i = 0; i < 4; ++i)                                           \
            af[i] = *(const bf16x8*)(&As[(BUF)][0] + (wm + i * 16 + l16) * 32 + quad * 8); \
        _Pragma("unroll")                                                     \
        for (int j = 0; j < 2; ++j)                                           \
            bfr[j] = *(const bf16x8*)(&Bs[(BUF)][0] + (wn + j * 16 + l16) * 32 + quad * 8); \
        _Pragma("unroll")                                                     \
        for (int i = 0; i < 4; ++i)                                           \
            _Pragma("unroll")                                                 \
            for (int j = 0; j < 2; ++j)                                       \
                acc[i][j] = __builtin_amdgcn_mfma_f32_16x16x32_bf16(af[i], bfr[j], acc[i][j], 0, 0, 0); \
    } while (0)

    O_STAGE(0, 0);
    O_STAGE(1, 1);
    for (int step = 0; step < 32; ++step) {
        __builtin_amdgcn_s_barrier();            // A: WAR guard
        const int nxt = step + 2;
        if (nxt < 32) O_STAGE(nxt % 3, nxt);
        if (step < 30)      asm volatile("s_waitcnt vmcnt(4)" ::: "memory");
        else if (step < 31) asm volatile("s_waitcnt vmcnt(2)" ::: "memory");
        else                asm volatile("s_waitcnt vmcnt(0)" ::: "memory");
        __builtin_amdgcn_s_barrier();            // B: stage(step) visible
        __builtin_amdgcn_sched_barrier(0);
        O_COMP(step % 3);
    }
#undef O_STAGE
#undef O_COMP

    #pragma unroll
    for (int i = 0; i < 4; ++i)
        #pragma unroll
        for (int j = 0; j < 2; ++j)
            #pragma unroll
            for (int r = 0; r < 4; ++r)
                C[(size_t)(m0 + wm + i * 16 + quad * 4 + r) * D_MODEL
                  + n0 + wn + j * 16 + l16] = acc[i][j][r];
}

// Flash causal attention, 32-q 2-WAVE blocks (r6 direct-load regressed: 64-line
// gathers; r5 LDS-staged version had no saturated pipe — MFMA 16 / VALU 44 /
// LDS 44 / occ 29 — lockstep 4-wave blocks at only ~2-3 live blocks/CU).
// This version: q-tile 32 rows, waves = khalf split only, grid 2048 = 8 small
// independent blocks/CU (LDS 18.4KB x 8 = 147KB, VGPR<=128 via
// __launch_bounds__(128,4)). Same verified math: skip/mask at 32-granularity
// gk = 2*kt+khalf vs gq = qi; frag addresses / softmax / pack-shfl / PV /
// merge / transpose are the r0 code with the qhalf dimension deleted.
// bh = bid&31 -> XCD = bh%8: each XCD serves 4 heads (2MB K/V, L2-resident).
// Diag mask branch hoisted (wave-uniform) to drop 16 cndmask on non-diag tiles.
__global__ __launch_bounds__(128, 4) void attn_kernel(
    const unsigned short* __restrict__ Qm,
    const unsigned short* __restrict__ Km,
    const unsigned short* __restrict__ VtG,
    unsigned short* __restrict__ Om)
{
    const int bid = blockIdx.x;
    const int bh  = bid & 31;                  // XCD = bh % 8 under RR dispatch
    const int y   = bid >> 5, g = y & 15, sl = y >> 4;
    const int qi  = (sl == 0) ? 63 - g : (sl == 1) ? 32 + g : (sl == 2) ? 31 - g : g;
    const int h   = bh & 15;
    const int b   = bh >> 4;
    const int t     = threadIdx.x;
    const int khalf = t >> 6;                  // wave role: key half
    const int lane  = t & 63;
    const int l31   = lane & 31, h32 = lane >> 5;

    __shared__ __align__(16) unsigned short Ks[64 * 72];      // K tile [key][dk]
    __shared__ __align__(16) unsigned short Vt[64 * 72];      // V^T tile [dk][key]

    const size_t base = (size_t)b * SEQ * D_MODEL + (size_t)h * DKH;
    const unsigned short* Qh = Qm + base;
    const unsigned short* Kh = Km + base;
    const unsigned short* Vh = VtG + (size_t)h * DKH * MTOT + (size_t)b * SEQ;  // [dk][m]

    // Q B-frags (Q pre-scaled by log2e/8): B[n=q=l31][k=h32*8+j], 4 k-steps = dk 64
    const int qrow = qi * 32 + l31;
    bf16x8 qf[4];
    #pragma unroll
    for (int ks = 0; ks < 4; ++ks)
        qf[ks] = *(const bf16x8*)(Qh + (size_t)qrow * D_MODEL + ks * 16 + h32 * 8);

    f32x16 accOT[2] = {};   // O^T partial: col=l31=q, row=(reg&3)+8*(reg>>2)+4*h32=dk (+32*db)
    float  la[4] = {0.f, 0.f, 0.f, 0.f};   // 4-way split row-sum partials

    // staging: 128 lanes, lane covers 64B: row = t>>1, col = (t&1)*32 shorts
    const int srow = t >> 1, scol = (t & 1) * 32;
    const int kbase = khalf * 32;
    const int nt = (qi >> 1) + 1;              // 64-key tiles

    // prefetch K/V tile 0 into regs (4+4 uint4 per lane)
    uint4 kr[4], vr[4];
    {
        const unsigned short* kg = Kh + (size_t)srow * D_MODEL + scol;
        const unsigned short* vg = Vh + (size_t)srow * MTOT + scol;
        #pragma unroll
        for (int j = 0; j < 4; ++j) { kr[j] = *(const uint4*)(kg + 8 * j);
                                      vr[j] = *(const uint4*)(vg + 8 * j); }
    }

    for (int kt = 0; kt < nt; ++kt) {
        __syncthreads();   // prior iter's frag reads done
        #pragma unroll
        for (int j = 0; j < 4; ++j) {
            *(uint4*)(Ks + srow * 72 + scol + 8 * j) = kr[j];
            *(uint4*)(Vt + srow * 72 + scol + 8 * j) = vr[j];
        }
        __syncthreads();

        if (kt + 1 < nt) {     // prefetch next tile; overlaps compute below
            const unsigned short* kg = Kh + (size_t)((kt + 1) * 64 + srow) * D_MODEL + scol;
            const unsigned short* vg = Vh + (size_t)srow * MTOT + (kt + 1) * 64 + scol;
            #pragma unroll
            for (int j = 0; j < 4; ++j) { kr[j] = *(const uint4*)(kg + 8 * j);
                                          vr[j] = *(const uint4*)(vg + 8 * j); }
        }

        const int gk = 2 * kt + khalf;         // 32-key group index
        if (gk > qi) continue;                 // fully-masked half (last tile only)

        // S^T = K Q^T : A = K rows
        f32x16 sT = {};
        #pragma unroll
        for (int ks = 0; ks < 4; ++ks) {
            bf16x8 kf = *(const bf16x8*)(Ks + (kbase + l31) * 72 + ks * 16 + h32 * 8);
            sT = __builtin_amdgcn_mfma_f32_32x32x16_bf16(kf, qf[ks], sT, 0, 0, 0);
        }

        // p = exp2(s); diag group masks key(rloc) <= q(l31); branch is wave-uniform
        float pv[16];
        if (gk == qi) {
            #pragma unroll
            for (int reg = 0; reg < 16; ++reg) {
                const int rloc = (reg & 3) + 8 * (reg >> 2) + 4 * h32;   // key_local
                float v = (rloc <= l31) ? sT[reg] : -1e30f;
                float p = exp2f(v);
                la[reg & 3] += p;
                pv[reg] = p;
            }
        } else {
            #pragma unroll
            for (int reg = 0; reg < 16; ++reg) {
                float p = exp2f(sT[reg]);
                la[reg & 3] += p;
                pv[reg] = p;
            }
        }
        // pack pairs (consecutive regs = consecutive keys) and half-wave exchange
        unsigned int pk[8], pr[8];
        #pragma unroll
        for (int i = 0; i < 8; ++i) pk[i] = pack2bf(pv[2 * i], pv[2 * i + 1]);
        #pragma unroll
        for (int i = 0; i < 8; ++i) pr[i] = __shfl_xor(pk[i], 32, 64);

        // O^T += V^T P^T : A = V^T rows, B = P^T in regs
        #pragma unroll
        for (int ks2 = 0; ks2 < 2; ++ks2) {
            union { u32x4 u; bf16x8 b; } pf;
            pf.u[0] = h32 ? pr[4 * ks2 + 2] : pk[4 * ks2 + 0];
            pf.u[1] = h32 ? pr[4 * ks2 + 3] : pk[4 * ks2 + 1];
            pf.u[2] = h32 ? pk[4 * ks2 + 2] : pr[4 * ks2 + 0];
            pf.u[3] = h32 ? pk[4 * ks2 + 3] : pr[4 * ks2 + 1];
            #pragma unroll
            for (int db = 0; db < 2; ++db) {
                bf16x8 vf = *(const bf16x8*)(Vt + (db * 32 + l31) * 72 + kbase + ks2 * 16 + h32 * 8);
                accOT[db] = __builtin_amdgcn_mfma_f32_32x32x16_bf16(vf, pf.b, accOT[db], 0, 0, 0);
            }
        }
    }

    float l_s = (la[0] + la[1]) + (la[2] + la[3]);

    // ---- merge key halves (khalf 1 -> 0) through dead Ks ----
    __syncthreads();
    float* exO = (float*)Ks;   // 64 lanes x 36 floats (32 O + l + pad) = 9216 B
    if (khalf == 1) {
        #pragma unroll
        for (int db = 0; db < 2; ++db)
            #pragma unroll
            for (int c = 0; c < 4; ++c) {
                float4 v = { accOT[db][c*4], accOT[db][c*4+1], accOT[db][c*4+2], accOT[db][c*4+3] };
                *(float4*)(exO + lane * 36 + db * 16 + c * 4) = v;
            }
        exO[lane * 36 + 32] = l_s;
    }
    __syncthreads();
    float inv = 0.f;
    if (khalf == 0) {
        #pragma unroll
        for (int db = 0; db < 2; ++db)
            #pragma unroll
            for (int c = 0; c < 4; ++c) {
                float4 v = *(const float4*)(exO + lane * 36 + db * 16 + c * 4);
                accOT[db][c*4]   += v.x; accOT[db][c*4+1] += v.y;
                accOT[db][c*4+2] += v.z; accOT[db][c*4+3] += v.w;
            }
        l_s += exO[lane * 36 + 32];
        l_s += __shfl_xor(l_s, 32, 64);   // other h32 half of the same q
        inv = 1.f / l_s;
    }
    __syncthreads();   // merge reads done; Ks free for the transpose tile

    // ---- transpose O^T -> [q][dk] bf16 tile in Ks, then coalesced store ----
    unsigned short* Ot = Ks;   // [32][68] u16 = 4352 B
    if (khalf == 0) {
        const int row = l31;
        #pragma unroll
        for (int db = 0; db < 2; ++db)
            #pragma unroll
            for (int c = 0; c < 4; ++c) {
                // dk pairs: (8c+4*h32, +1) and (+2, +3)
                unsigned int w0 = pack2bf(accOT[db][4*c]   * inv, accOT[db][4*c+1] * inv);
                unsigned int w1 = pack2bf(accOT[db][4*c+2] * inv, accOT[db][4*c+3] * inv);
                const int off = db * 32 + 8 * c + 4 * h32;
                *(unsigned int*)(Ot + row * 68 + off)     = w0;
                *(unsigned int*)(Ot + row * 68 + off + 2) = w1;
            }
    }
    __syncthreads();
    {
        const int row = t >> 2, col = (t & 3) * 16;   // 32 rows x 64 dk
        uint4 o0 = *(const uint4*)(Ot + row * 68 + col);
        uint4 o1 = *(const uint4*)(Ot + row * 68 + col + 8);
        unsigned short* dst = Om + (size_t)(b * SEQ + qi * 32 + row) * D_MODEL + h * DKH + col;
        *(uint4*)(dst)     = o0;
        *(uint4*)(dst + 8) = o1;
    }
}

extern "C" void kernel_launch(void* const* d_in, const int* in_sizes, int n_in,
                              void* d_out, int out_size, void* d_ws, size_t ws_size,
                              hipStream_t stream) {
    const float* x   = (const float*)d_in[0];
    const float* w_q = (const float*)d_in[1];
    const float* w_k = (const float*)d_in[2];
    const float* w_v = (const float*)d_in[3];
    const float* w_o = (const float*)d_in[4];
    float* out = (float*)d_out;

    // ws (48 MB): xb 8 | weights 4x2 | Qb 8 | Kb 8 | VtG 8 | Ab 8
    unsigned short* xb  = (unsigned short*)d_ws;
    unsigned short* wqb = xb  + (size_t)MTOT * D_MODEL;
    unsigned short* wkb = wqb + (size_t)D_MODEL * D_MODEL;
    unsigned short* wvb = wkb + (size_t)D_MODEL * D_MODEL;
    unsigned short* wob = wvb + (size_t)D_MODEL * D_MODEL;
    unsigned short* Qb  = wob + (size_t)D_MODEL * D_MODEL;
    unsigned short* Kb  = Qb  + (size_t)MTOT * D_MODEL;
    unsigned short* VtG = Kb  + (size_t)MTOT * D_MODEL;   // V^T [1024][4096]
    unsigned short* Ab  = VtG + (size_t)MTOT * D_MODEL;

    cvt_all<<<dim3(2048 + 4 * 512), dim3(256), 0, stream>>>(
        x, w_q, w_k, w_v, w_o, xb, wqb, wkb, wvb, wob);
    // fused QKV projection, depth-2 counted-vmcnt pipeline; x staged once.
    // Q scale = (1/8) * log2(e) so attention can use exp2.
    qkv_fused<<<dim3(MTOT / 128, D_MODEL / 128), dim3(512), 0, stream>>>(
        xb, wqb, wkb, wvb, Qb, Kb, VtG, 0.125f * 1.44269504f);
    // causal flash attention: 32-q 2-wave blocks, 8 blocks/CU
    attn_kernel<<<dim3(2048), dim3(128), 0, stream>>>(Qb, Kb, VtG, Ab);
    // output projection -> fp32 (depth-2 counted-vmcnt pipeline)
    gemm_o<<<dim3(MTOT / 128, D_MODEL / 128), dim3(512), 0, stream>>>(Ab, wob, out);
}

// Round 8
// 162.667 us; speedup vs baseline: 1.8037x; 1.8037x over previous
//
#include <hip/hip_runtime.h>
#include <hip/hip_bf16.h>
#include <stdint.h>

#define D_MODEL 1024
#define NHEADS  16
#define DKH     64
#define BATCH   2
#define SEQ     2048
#define MTOT    (BATCH*SEQ)   // 4096

typedef __attribute__((ext_vector_type(8)))  short bf16x8;   // 8 bf16 = 4 VGPRs
typedef __attribute__((ext_vector_type(4)))  float f32x4;
typedef __attribute__((ext_vector_type(16))) float f32x16;
typedef __attribute__((ext_vector_type(4)))  unsigned int u32x4;

__device__ inline unsigned short f2bf(float f) {
    __hip_bfloat16 h = __float2bfloat16(f);
    return *reinterpret_cast<unsigned short*>(&h);
}
__device__ inline unsigned int pack2bf(float a, float b) {   // low=a, high=b (RNE)
    __hip_bfloat162 h = __float22bfloat162_rn(float2{a, b});
    return *reinterpret_cast<unsigned int*>(&h);
}

// async global->LDS, 16B per lane; LDS dest = wave-uniform base + lane*16 (m97/m104)
__device__ inline void gl2lds16(const unsigned short* g, unsigned short* l) {
    __builtin_amdgcn_global_load_lds(
        (const __attribute__((address_space(1))) void*)g,
        (__attribute__((address_space(3))) void*)l,
        16, 0, 0);
}

// One-shot fp32 -> bf16 conversion of x and the 4 weight matrices.
__global__ __launch_bounds__(256) void cvt_all(
    const float* __restrict__ x,  const float* __restrict__ wq,
    const float* __restrict__ wk, const float* __restrict__ wv,
    const float* __restrict__ wo,
    unsigned short* __restrict__ xb,  unsigned short* __restrict__ wqb,
    unsigned short* __restrict__ wkb, unsigned short* __restrict__ wvb,
    unsigned short* __restrict__ wob)
{
    int bid = blockIdx.x;
    const float* s; unsigned short* d; size_t base;
    if (bid < 2048) { s = x; d = xb; base = (size_t)bid * 2048; }
    else {
        int w  = (bid - 2048) >> 9;
        int wb = (bid - 2048) & 511;
        s = (w == 0) ? wq : (w == 1) ? wk : (w == 2) ? wv : wo;
        d = (w == 0) ? wqb : (w == 1) ? wkb : (w == 2) ? wvb : wob;
        base = (size_t)wb * 2048;
    }
    size_t i = base + (size_t)threadIdx.x * 8;
    float4 a = *(const float4*)(s + i);
    float4 b = *(const float4*)(s + i + 4);
    unsigned short t8[8] = {f2bf(a.x), f2bf(a.y), f2bf(a.z), f2bf(a.w),
                            f2bf(b.x), f2bf(b.y), f2bf(b.z), f2bf(b.w)};
    *(uint4*)(d + i) = *(uint4*)t8;
}

// Fused QKV projection, depth-2 counted-vmcnt pipeline with LITERAL buffer
// indices (unrolled by 3). r3/r4/r5 all landed at ~46.5us because runtime
// buffer indices (step%3) defeated LDS alias analysis: the compiler inserted
// a conservative s_waitcnt vmcnt(0) before the ds_reads (can't prove the
// in-flight global_load_lds writes don't alias), silently restoring the full
// drain. Literal indices give disjoint constant LDS ranges -> the counted
// vmcnt(8) survives as the only wait (m218 T4 mechanism).
// grid (32, 8) = 256 blocks, 512 thr (8 waves: wm=(w>>2)*64, wn=(w&3)*32).
__global__ __launch_bounds__(512, 2) void qkv_fused(
    const unsigned short* __restrict__ X,
    const unsigned short* __restrict__ Wq,
    const unsigned short* __restrict__ Wk,
    const unsigned short* __restrict__ Wv,
    unsigned short* __restrict__ Qo,
    unsigned short* __restrict__ Ko,
    unsigned short* __restrict__ Vto,
    float qscale)
{
    const int id = blockIdx.x + 32 * blockIdx.y;   // 256 blocks, 256%8==0
    const int sw = (id & 7) * 32 + (id >> 3);      // XCD c -> contiguous chunk
    const int m0 = (sw & 31) * 128;                // x-row tile
    const int n0 = (sw >> 5) * 128;                // weight-row tile

    // [buf 0..2][128 x 32 shorts] per tile; 4 tiles x 3 buf = 96 KiB
    __shared__ __align__(16) unsigned short Xs[3][128 * 32];
    __shared__ __align__(16) unsigned short Bq[3][128 * 32];
    __shared__ __align__(16) unsigned short Bk[3][128 * 32];
    __shared__ __align__(16) unsigned short Bv[3][128 * 32];

    const int t = threadIdx.x;
    const int wave = t >> 6, lane = t & 63;
    const int quad = lane >> 4, l16 = lane & 15;
    const int wm = (wave >> 2) * 64;
    const int wn = (wave & 3) * 32;

    // staging: wave w covers tile (w>>1), rows [(w&1)*64, +64) in 4 groups of 16
    const int stile = wave >> 1;
    const int srow  = (wave & 1) * 64 + (lane >> 2);
    const int schk  = (lane & 3) * 8;
    const unsigned short* gsrc = (stile == 0) ? X : (stile == 1) ? Wq :
                                 (stile == 2) ? Wk : Wv;
    const int grow0 = (stile == 0) ? m0 : n0;
    const unsigned short* Sg = gsrc + (size_t)(grow0 + srow) * D_MODEL + schk;
    unsigned short* LdB = ((stile == 0) ? &Xs[0][0] : (stile == 1) ? &Bq[0][0] :
                           (stile == 2) ? &Bk[0][0] : &Bv[0][0])
                          + (wave & 1) * 64 * 32;   // wave-uniform base

    f32x4 aQ[4][2] = {}, aK[4][2] = {}, aV[2][4] = {};

// BUF must be a LITERAL so the LDS dest range is a compile-time constant.
#define QKV_STAGE(BUF, STEP)                                                  \
    do {                                                                      \
        _Pragma("unroll")                                                     \
        for (int g = 0; g < 4; ++g)                                           \
            gl2lds16(Sg + (STEP) * 32 + (size_t)g * 16 * D_MODEL,             \
                     LdB + (BUF) * 4096 + g * 512);                           \
    } while (0)

#define QKV_COMP(BUF)                                                         \
    do {                                                                      \
        bf16x8 xa[4], fq[2], fk[2], fv[2];                                    \
        _Pragma("unroll")                                                     \
        for (int i = 0; i < 4; ++i)                                           \
            xa[i] = *(const bf16x8*)(&Xs[(BUF)][0] + (wm + i * 16 + l16) * 32 + quad * 8); \
        _Pragma("unroll")                                                     \
        for (int j = 0; j < 2; ++j) {                                         \
            fq[j] = *(const bf16x8*)(&Bq[(BUF)][0] + (wn + j * 16 + l16) * 32 + quad * 8); \
            fk[j] = *(const bf16x8*)(&Bk[(BUF)][0] + (wn + j * 16 + l16) * 32 + quad * 8); \
            fv[j] = *(const bf16x8*)(&Bv[(BUF)][0] + (wn + j * 16 + l16) * 32 + quad * 8); \
        }                                                                     \
        _Pragma("unroll")                                                     \
        for (int i = 0; i < 4; ++i)                                           \
            _Pragma("unroll")                                                 \
            for (int j = 0; j < 2; ++j) {                                     \
                aQ[i][j] = __builtin_amdgcn_mfma_f32_16x16x32_bf16(xa[i], fq[j], aQ[i][j], 0, 0, 0); \
                aK[i][j] = __builtin_amdgcn_mfma_f32_16x16x32_bf16(xa[i], fk[j], aK[i][j], 0, 0, 0); \
                aV[j][i] = __builtin_amdgcn_mfma_f32_16x16x32_bf16(fv[j], xa[i], aV[j][i], 0, 0, 0); \
            }                                                                 \
    } while (0)

// one pipeline step: compute CBUF, stage (step+2) into SBUF, counted wait
#define QKV_STEP(CBUF, SBUF, STEP)                                            \
    do {                                                                      \
        __builtin_amdgcn_s_barrier();   /* A: compute(step-1) done -> SBUF free */ \
        QKV_STAGE(SBUF, (STEP) + 2);                                          \
        asm volatile("s_waitcnt vmcnt(8)" ::: "memory");  /* stage(step) landed */ \
        __builtin_amdgcn_s_barrier();   /* B: stage(step) visible to all */   \
        __builtin_amdgcn_sched_barrier(0);                                    \
        QKV_COMP(CBUF);                                                       \
    } while (0)

    QKV_STAGE(0, 0);          // 4 loads in flight
    QKV_STAGE(1, 1);          // 8 loads in flight
    for (int s3 = 0; s3 < 30; s3 += 3) {   // steps 0..29; stages 2..31 issued
        QKV_STEP(0, 2, s3);
        QKV_STEP(1, 0, s3 + 1);
        QKV_STEP(2, 1, s3 + 2);
    }
    // step 30 (buf 0): nothing left to stage; stages 30,31 in flight
    __builtin_amdgcn_s_barrier();
    asm volatile("s_waitcnt vmcnt(4)" ::: "memory");
    __builtin_amdgcn_s_barrier();
    __builtin_amdgcn_sched_barrier(0);
    QKV_COMP(0);
    // step 31 (buf 1)
    __builtin_amdgcn_s_barrier();
    asm volatile("s_waitcnt vmcnt(0)" ::: "memory");
    __builtin_amdgcn_s_barrier();
    __builtin_amdgcn_sched_barrier(0);
    QKV_COMP(1);
#undef QKV_STEP
#undef QKV_STAGE
#undef QKV_COMP

    #pragma unroll
    for (int i = 0; i < 4; ++i)
        #pragma unroll
        for (int j = 0; j < 2; ++j)
            #pragma unroll
            for (int r = 0; r < 4; ++r) {
                const int mr = m0 + wm + i * 16 + quad * 4 + r;
                const int nc = n0 + wn + j * 16 + l16;
                Qo[(size_t)mr * D_MODEL + nc] = f2bf(aQ[i][j][r] * qscale);
                Ko[(size_t)mr * D_MODEL + nc] = f2bf(aK[i][j][r]);
                // V^T: row = weight-side of aV, col = x-side
                Vto[(size_t)(n0 + wn + j * 16 + quad * 4 + r) * MTOT
                    + (m0 + wm + i * 16 + l16)] = f2bf(aV[j][i][r]);
            }
}

// Output projection C_fp32[M,N] = A[M,K] @ W[N,K]^T, 128^2 tile, 512 thr,
// depth-2 counted-vmcnt pipeline, LITERAL buffer indices (same fix as qkv).
__global__ __launch_bounds__(512, 2) void gemm_o(
    const unsigned short* __restrict__ A,
    const unsigned short* __restrict__ W,
    float* __restrict__ C)
{
    const int id = blockIdx.x + 32 * blockIdx.y;
    const int sw = (id & 7) * 32 + (id >> 3);
    const int m0 = (sw & 31) * 128, n0 = (sw >> 5) * 128;

    __shared__ __align__(16) unsigned short As[3][128 * 32];
    __shared__ __align__(16) unsigned short Bs[3][128 * 32];   // 48 KiB

    const int t = threadIdx.x, wave = t >> 6, lane = t & 63;
    const int quad = lane >> 4, l16 = lane & 15;
    const int wm = (wave >> 2) * 64, wn = (wave & 3) * 32;

    // staging: wave w covers tile (w>>2), rows [(w&3)*32, +32) in 2 groups of 16
    const int stile = wave >> 2;
    const int srow  = (wave & 3) * 32 + (lane >> 2);
    const int schk  = (lane & 3) * 8;
    const unsigned short* Sg = (stile ? W : A)
        + (size_t)((stile ? n0 : m0) + srow) * D_MODEL + schk;
    unsigned short* LdB = (stile ? &Bs[0][0] : &As[0][0]) + (wave & 3) * 32 * 32;

    f32x4 acc[4][2] = {};

#define O_STAGE(BUF, STEP)                                                    \
    do {                                                                      \
        _Pragma("unroll")                                                     \
        for (int g = 0; g < 2; ++g)                                           \
            gl2lds16(Sg + (STEP) * 32 + (size_t)g * 16 * D_MODEL,             \
                     LdB + (BUF) * 4096 + g * 512);                           \
    } while (0)

#define O_COMP(BUF)                                                           \
    do {                                                                      \
        bf16x8 af[4], bfr[2];                                                 \
        _Pragma("unroll")                                                     \
        for (int i = 0; i < 4; ++i)                                           \
            af[i] = *(const bf16x8*)(&As[(BUF)][0] + (wm + i * 16 + l16) * 32 + quad * 8); \
        _Pragma("unroll")                                                     \
        for (int j = 0; j < 2; ++j)                                           \
            bfr[j] = *(const bf16x8*)(&Bs[(BUF)][0] + (wn + j * 16 + l16) * 32 + quad * 8); \
        _Pragma("unroll")                                                     \
        for (int i = 0; i < 4; ++i)                                           \
            _Pragma("unroll")                                                 \
            for (int j = 0; j < 2; ++j)                                       \
                acc[i][j] = __builtin_amdgcn_mfma_f32_16x16x32_bf16(af[i], bfr[j], acc[i][j], 0, 0, 0); \
    } while (0)

#define O_STEP(CBUF, SBUF, STEP)                                              \
    do {                                                                      \
        __builtin_amdgcn_s_barrier();                                         \
        O_STAGE(SBUF, (STEP) + 2);                                            \
        asm volatile("s_waitcnt vmcnt(4)" ::: "memory");                      \
        __builtin_amdgcn_s_barrier();                                         \
        __builtin_amdgcn_sched_barrier(0);                                    \
        O_COMP(CBUF);                                                         \
    } while (0)

    O_STAGE(0, 0);
    O_STAGE(1, 1);
    for (int s3 = 0; s3 < 30; s3 += 3) {
        O_STEP(0, 2, s3);
        O_STEP(1, 0, s3 + 1);
        O_STEP(2, 1, s3 + 2);
    }
    __builtin_amdgcn_s_barrier();
    asm volatile("s_waitcnt vmcnt(2)" ::: "memory");
    __builtin_amdgcn_s_barrier();
    __builtin_amdgcn_sched_barrier(0);
    O_COMP(0);
    __builtin_amdgcn_s_barrier();
    asm volatile("s_waitcnt vmcnt(0)" ::: "memory");
    __builtin_amdgcn_s_barrier();
    __builtin_amdgcn_sched_barrier(0);
    O_COMP(1);
#undef O_STEP
#undef O_STAGE
#undef O_COMP

    #pragma unroll
    for (int i = 0; i < 4; ++i)
        #pragma unroll
        for (int j = 0; j < 2; ++j)
            #pragma unroll
            for (int r = 0; r < 4; ++r)
                C[(size_t)(m0 + wm + i * 16 + quad * 4 + r) * D_MODEL
                  + n0 + wn + j * 16 + l16] = acc[i][j][r];
}

// Flash causal attention — r5-EXACT verified kernel (64-q blocks, split-key
// waves, 2-barrier tile loop, 18 KiB LDS, 256 thr, grid (32,32) balanced;
// 44 us measured). r6 (direct reg loads) and r7 (128-thr 32-q) both regressed
// (uncoalesced gathers / VGPR spill to scratch). Reverted.
__global__ __launch_bounds__(256, 4) void attn_kernel(
    const unsigned short* __restrict__ Qm,
    const unsigned short* __restrict__ Km,
    const unsigned short* __restrict__ VtG,
    unsigned short* __restrict__ Om)
{
    const int bh = blockIdx.x;
    const int y  = blockIdx.y, g = y & 7, sl = y >> 3;
    const int qt = (sl == 0) ? 31 - g : (sl == 1) ? 16 + g : (sl == 2) ? 15 - g : g;
    const int h  = bh & 15;
    const int b  = bh >> 4;
    const int t     = threadIdx.x;
    const int wave  = t >> 6, lane = t & 63;
    const int qhalf = wave >> 1, khalf = wave & 1;
    const int l31   = lane & 31, h32 = lane >> 5;

    __shared__ __align__(16) unsigned short Ks[64 * 72];      // K tile [key][dk]
    __shared__ __align__(16) unsigned short Vt[64 * 72];      // V^T tile [dk][key]

    const size_t base = (size_t)b * SEQ * D_MODEL + (size_t)h * DKH;
    const unsigned short* Qh = Qm + base;
    const unsigned short* Kh = Km + base;
    const unsigned short* Vh = VtG + (size_t)h * DKH * MTOT + (size_t)b * SEQ;  // [dk][m]

    // Q B-frags (Q pre-scaled by log2e/8): B[n=q=l31][k=h32*8+j], 4 k-steps = dk 64
    const int qrow = qt * 64 + qhalf * 32 + l31;
    bf16x8 qf[4];
    #pragma unroll
    for (int ks = 0; ks < 4; ++ks)
        qf[ks] = *(const bf16x8*)(Qh + (size_t)qrow * D_MODEL + ks * 16 + h32 * 8);

    f32x16 accOT[2] = {};   // O^T partial: col=l31=q, row=(reg&3)+8*(reg>>2)+4*h32=dk (+32*db)
    float  la[4] = {0.f, 0.f, 0.f, 0.f};   // 4-way split row-sum partials

    const int srow = t >> 2, scol = (t & 3) * 16;
    const int kbase = khalf * 32;

    // prefetch K/V tile 0 into regs
    uint4 kr0, kr1, vr0, vr1;
    {
        const unsigned short* ks = Kh + (size_t)srow * D_MODEL + scol;
        kr0 = *(const uint4*)ks; kr1 = *(const uint4*)(ks + 8);
        const unsigned short* vs = Vh + (size_t)srow * MTOT + scol;
        vr0 = *(const uint4*)vs; vr1 = *(const uint4*)(vs + 8);
    }

    for (int kt = 0; kt <= qt; ++kt) {
        __syncthreads();   // prior iter's frag reads done
        *(uint4*)(Ks + srow * 72 + scol)     = kr0;
        *(uint4*)(Ks + srow * 72 + scol + 8) = kr1;
        *(uint4*)(Vt + srow * 72 + scol)     = vr0;
        *(uint4*)(Vt + srow * 72 + scol + 8) = vr1;
        __syncthreads();

        if (kt < qt) {     // prefetch next tile; overlaps compute below
            const unsigned short* ks = Kh + (size_t)((kt + 1) * 64 + srow) * D_MODEL + scol;
            kr0 = *(const uint4*)ks; kr1 = *(const uint4*)(ks + 8);
            const unsigned short* vs = Vh + (size_t)srow * MTOT + (kt + 1) * 64 + scol;
            vr0 = *(const uint4*)vs; vr1 = *(const uint4*)(vs + 8);
        }

        const bool diag = (kt == qt);
        if (diag && khalf > qhalf) continue;   // fully-masked quarter: skip

        // S^T = K Q^T : A=K rows (same LDS bytes as before, roles swapped)
        f32x16 sT = {};
        #pragma unroll
        for (int ks = 0; ks < 4; ++ks) {
            bf16x8 kf = *(const bf16x8*)(Ks + (kbase + l31) * 72 + ks * 16 + h32 * 8);
            sT = __builtin_amdgcn_mfma_f32_32x32x16_bf16(kf, qf[ks], sT, 0, 0, 0);
        }

        // p = exp2(s); mask on equal-half diag quarter: keep key(rloc) <= q(l31)
        const bool maskq = diag && (khalf == qhalf);
        float pv[16];
        #pragma unroll
        for (int reg = 0; reg < 16; ++reg) {
            const int rloc = (reg & 3) + 8 * (reg >> 2) + 4 * h32;   // key_local
            float v = sT[reg];
            if (maskq) v = (rloc <= l31) ? v : -1e30f;
            float p = exp2f(v);
            la[reg & 3] += p;
            pv[reg] = p;
        }
        // pack pairs (consecutive regs = consecutive keys) and half-wave exchange
        unsigned int pk[8], pr[8];
        #pragma unroll
        for (int i = 0; i < 8; ++i) pk[i] = pack2bf(pv[2 * i], pv[2 * i + 1]);
        #pragma unroll
        for (int i = 0; i < 8; ++i) pr[i] = __shfl_xor(pk[i], 32, 64);

        // O^T += V^T P^T : A = V^T rows (same bytes as before), B = P^T in regs
        #pragma unroll
        for (int ks2 = 0; ks2 < 2; ++ks2) {
            union { u32x4 u; bf16x8 b; } pf;
            pf.u[0] = h32 ? pr[4 * ks2 + 2] : pk[4 * ks2 + 0];
            pf.u[1] = h32 ? pr[4 * ks2 + 3] : pk[4 * ks2 + 1];
            pf.u[2] = h32 ? pk[4 * ks2 + 2] : pr[4 * ks2 + 0];
            pf.u[3] = h32 ? pk[4 * ks2 + 3] : pr[4 * ks2 + 1];
            #pragma unroll
            for (int db = 0; db < 2; ++db) {
                bf16x8 vf = *(const bf16x8*)(Vt + (db * 32 + l31) * 72 + kbase + ks2 * 16 + h32 * 8);
                accOT[db] = __builtin_amdgcn_mfma_f32_32x32x16_bf16(vf, pf.b, accOT[db], 0, 0, 0);
            }
        }
    }

    float l_s = (la[0] + la[1]) + (la[2] + la[3]);

    // ---- merge key halves (khalf 1 -> 0) through dead Ks/Vt ----
    __syncthreads();
    float* exO = (qhalf == 0) ? (float*)Ks : (float*)Vt;   // 64 lanes x 36 floats (32 O + l + pad)
    if (khalf == 1) {
        #pragma unroll
        for (int db = 0; db < 2; ++db)
            #pragma unroll
            for (int c = 0; c < 4; ++c) {
                float4 v = { accOT[db][c*4], accOT[db][c*4+1], accOT[db][c*4+2], accOT[db][c*4+3] };
                *(float4*)(exO + lane * 36 + db * 16 + c * 4) = v;
            }
        exO[lane * 36 + 32] = l_s;
    }
    __syncthreads();
    float inv = 0.f;
    if (khalf == 0) {
        #pragma unroll
        for (int db = 0; db < 2; ++db)
            #pragma unroll
            for (int c = 0; c < 4; ++c) {
                float4 v = *(const float4*)(exO + lane * 36 + db * 16 + c * 4);
                accOT[db][c*4]   += v.x; accOT[db][c*4+1] += v.y;
                accOT[db][c*4+2] += v.z; accOT[db][c*4+3] += v.w;
            }
        l_s += exO[lane * 36 + 32];
        l_s += __shfl_xor(l_s, 32, 64);   // other h32 half of the same q
        inv = 1.f / l_s;
    }
    __syncthreads();   // merge reads done; Ks free for the transpose tile

    // ---- transpose O^T -> [q][dk] bf16 tile in Ks, then coalesced store ----
    unsigned short* Ot = Ks;   // [64][68] u16
    if (khalf == 0) {
        const int row = qhalf * 32 + l31;
        #pragma unroll
        for (int db = 0; db < 2; ++db)
            #pragma unroll
            for (int c = 0; c < 4; ++c) {
                // dk pairs: (8c+4*h32, +1) and (+2, +3)
                unsigned int w0 = pack2bf(accOT[db][4*c]   * inv, accOT[db][4*c+1] * inv);
                unsigned int w1 = pack2bf(accOT[db][4*c+2] * inv, accOT[db][4*c+3] * inv);
                const int off = db * 32 + 8 * c + 4 * h32;
                *(unsigned int*)(Ot + row * 68 + off)     = w0;
                *(unsigned int*)(Ot + row * 68 + off + 2) = w1;
            }
    }
    __syncthreads();
    {
        const int row = t >> 2, col = (t & 3) * 16;
        uint4 o0 = *(const uint4*)(Ot + row * 68 + col);
        uint4 o1 = *(const uint4*)(Ot + row * 68 + col + 8);
        unsigned short* dst = Om + (size_t)(b * SEQ + qt * 64 + row) * D_MODEL + h * DKH + col;
        *(uint4*)(dst)     = o0;
        *(uint4*)(dst + 8) = o1;
    }
}

extern "C" void kernel_launch(void* const* d_in, const int* in_sizes, int n_in,
                              void* d_out, int out_size, void* d_ws, size_t ws_size,
                              hipStream_t stream) {
    const float* x   = (const float*)d_in[0];
    const float* w_q = (const float*)d_in[1];
    const float* w_k = (const float*)d_in[2];
    const float* w_v = (const float*)d_in[3];
    const float* w_o = (const float*)d_in[4];
    float* out = (float*)d_out;

    // ws (48 MB): xb 8 | weights 4x2 | Qb 8 | Kb 8 | VtG 8 | Ab 8
    unsigned short* xb  = (unsigned short*)d_ws;
    unsigned short* wqb = xb  + (size_t)MTOT * D_MODEL;
    unsigned short* wkb = wqb + (size_t)D_MODEL * D_MODEL;
    unsigned short* wvb = wkb + (size_t)D_MODEL * D_MODEL;
    unsigned short* wob = wvb + (size_t)D_MODEL * D_MODEL;
    unsigned short* Qb  = wob + (size_t)D_MODEL * D_MODEL;
    unsigned short* Kb  = Qb  + (size_t)MTOT * D_MODEL;
    unsigned short* VtG = Kb  + (size_t)MTOT * D_MODEL;   // V^T [1024][4096]
    unsigned short* Ab  = VtG + (size_t)MTOT * D_MODEL;

    cvt_all<<<dim3(2048 + 4 * 512), dim3(256), 0, stream>>>(
        x, w_q, w_k, w_v, w_o, xb, wqb, wkb, wvb, wob);
    // fused QKV projection, depth-2 counted-vmcnt pipeline (literal buf idx).
    // Q scale = (1/8) * log2(e) so attention can use exp2.
    qkv_fused<<<dim3(MTOT / 128, D_MODEL / 128), dim3(512), 0, stream>>>(
        xb, wqb, wkb, wvb, Qb, Kb, VtG, 0.125f * 1.44269504f);
    // balanced causal flash attention (r5-exact verified structure)
    attn_kernel<<<dim3(BATCH * NHEADS, 32), dim3(256), 0, stream>>>(Qb, Kb, VtG, Ab);
    // output projection -> fp32 (depth-2 counted-vmcnt pipeline, literal buf idx)
    gemm_o<<<dim3(MTOT / 128, D_MODEL / 128), dim3(512), 0, stream>>>(Ab, wob, out);
}